// Round 1
// baseline (2380.871 us; speedup 1.0000x reference)
//
#include <hip/hip_runtime.h>

#define UCNT 100000
#define ICNT 50000
#define BB   3
#define NNZE 2400000
#define NN   150000   // UCNT + ICNT

// ---------------- init: cur = acc = ego (broadcast to 3 behaviors) ----------
__global__ __launch_bounds__(256) void k_init(const float* __restrict__ ue,
                                              const float* __restrict__ ie,
                                              float* __restrict__ cur,
                                              float* __restrict__ acc){
  long long idx = (long long)blockIdx.x * blockDim.x + threadIdx.x;  // float4 index
  const long long total = (long long)BB * NN * 16;
  if (idx >= total) return;
  long long within = idx % ((long long)NN * 16);
  long long n = within >> 4;
  int c = (int)(within & 15);
  float4 v;
  if (n < UCNT) v = ((const float4*)ue)[n * 16 + c];
  else          v = ((const float4*)ie)[(n - UCNT) * 16 + c];
  ((float4*)cur)[idx] = v;
  ((float4*)acc)[idx] = v;
}

__global__ __launch_bounds__(256) void k_zero(int* __restrict__ p, long long n){
  long long i = (long long)blockIdx.x * blockDim.x + threadIdx.x;
  if (i < n) p[i] = 0;
}

// ---------------- CSR build ------------------------------------------------
__global__ __launch_bounds__(256) void k_hist(const int* __restrict__ rows,
                                              int* __restrict__ cnt){
  long long i = (long long)blockIdx.x * blockDim.x + threadIdx.x;
  if (i >= (long long)BB * NNZE) return;
  int b = (int)(i / NNZE);
  atomicAdd(&cnt[b * NN + rows[i]], 1);
}

__global__ __launch_bounds__(1024) void k_scan(const int* __restrict__ cnt,
                                               int* __restrict__ rp,
                                               int* __restrict__ tp){
  int b = blockIdx.x;
  const int* c = cnt + (long long)b * NN;
  int* rpo = rp + (long long)b * (NN + 1);
  int* tpo = tp + (long long)b * NN;
  __shared__ int sd[1024];
  __shared__ int carry;
  if (threadIdx.x == 0) carry = 0;
  __syncthreads();
  for (int base = 0; base < NN; base += 1024){
    int i = base + threadIdx.x;
    int v = (i < NN) ? c[i] : 0;
    sd[threadIdx.x] = v;
    __syncthreads();
    for (int off = 1; off < 1024; off <<= 1){
      int t = (threadIdx.x >= off) ? sd[threadIdx.x - off] : 0;
      __syncthreads();
      sd[threadIdx.x] += t;
      __syncthreads();
    }
    int incl = sd[threadIdx.x];
    int ctot = sd[1023];
    int excl = carry + incl - v;
    if (i < NN){ rpo[i] = excl; tpo[i] = excl; }
    __syncthreads();
    if (threadIdx.x == 0) carry += ctot;
    __syncthreads();
  }
  if (threadIdx.x == 0) rpo[NN] = carry;  // == NNZE
}

__global__ __launch_bounds__(256) void k_scatter(const int* __restrict__ rows,
                                                 const int* __restrict__ cols,
                                                 const float* __restrict__ vals,
                                                 int* __restrict__ tp,
                                                 int* __restrict__ ccol,
                                                 float* __restrict__ cval){
  long long i = (long long)blockIdx.x * blockDim.x + threadIdx.x;
  if (i >= (long long)BB * NNZE) return;
  int b = (int)(i / NNZE);
  int pos = atomicAdd(&tp[b * NN + rows[i]], 1);
  long long o = (long long)b * NNZE + pos;
  ccol[o] = cols[i];
  cval[o] = vals[i];
}

// ---------------- SpMM: one wave per (behavior,row), lane = element --------
__global__ __launch_bounds__(256) void k_spmm(const int* __restrict__ rp,
                                              const int* __restrict__ ccol,
                                              const float* __restrict__ cval,
                                              const float* __restrict__ cur,
                                              float* __restrict__ nxt,
                                              float* __restrict__ acc){
  int wid = blockIdx.x * (blockDim.x >> 6) + (threadIdx.x >> 6);
  int lane = threadIdx.x & 63;
  if (wid >= BB * NN) return;
  int b = wid / NN;
  int row = wid - b * NN;
  b   = __builtin_amdgcn_readfirstlane(b);
  row = __builtin_amdgcn_readfirstlane(row);
  const int* rpo = rp + (long long)b * (NN + 1);
  int s0 = __builtin_amdgcn_readfirstlane(rpo[row]);
  int s1 = __builtin_amdgcn_readfirstlane(rpo[row + 1]);
  const float* xb = cur + (long long)b * NN * 64;
  const int*   cc = ccol + (long long)b * NNZE;
  const float* cv = cval + (long long)b * NNZE;
  float s = 0.f;
  int e = s0;
  for (; e + 1 < s1; e += 2){
    int c0 = __builtin_amdgcn_readfirstlane(cc[e]);
    int c1 = __builtin_amdgcn_readfirstlane(cc[e + 1]);
    float v0 = cv[e], v1 = cv[e + 1];
    s += v0 * xb[(long long)c0 * 64 + lane];
    s += v1 * xb[(long long)c1 * 64 + lane];
  }
  if (e < s1){
    int c0 = __builtin_amdgcn_readfirstlane(cc[e]);
    s += cv[e] * xb[(long long)c0 * 64 + lane];
  }
  long long o = (long long)wid * 64 + lane;
  nxt[o] = s;
  acc[o] += s;
}

// ---------------- attention epilogue: one thread per node ------------------
__device__ __forceinline__ float fast_tanh(float x){
  float xc = fminf(fmaxf(x, -15.f), 15.f);
  float t = __expf(2.f * xc);
  return (t - 1.f) / (t + 1.f);
}

__global__ __launch_bounds__(256) void k_att(const float* __restrict__ acc,
                                             const float* __restrict__ W1,
                                             const float* __restrict__ W2,
                                             float* __restrict__ out){
  __shared__ float sW1[BB * 64 * 16];
  __shared__ float sW2[BB * 16];
  for (int i = threadIdx.x; i < BB * 64 * 16; i += blockDim.x) sW1[i] = W1[i];
  if (threadIdx.x < BB * 16) sW2[threadIdx.x] = W2[threadIdx.x];
  __syncthreads();
  int n = blockIdx.x * blockDim.x + threadIdx.x;
  if (n >= NN) return;

  float sc[BB][BB];   // [head][behavior]
  for (int b = 0; b < BB; ++b){
    const float4* src = (const float4*)(acc + ((long long)b * NN + n) * 64);
    float4 v[16];
    #pragma unroll
    for (int c = 0; c < 16; ++c){
      v[c] = src[c];
      v[c].x *= 0.25f; v[c].y *= 0.25f; v[c].z *= 0.25f; v[c].w *= 0.25f;
    }
    for (int h = 0; h < BB; ++h){
      float hid[16];
      #pragma unroll
      for (int k = 0; k < 16; ++k) hid[k] = 0.f;
      #pragma unroll
      for (int c = 0; c < 16; ++c){
        const float* w = &sW1[h * 1024 + c * 64];
        #pragma unroll
        for (int k = 0; k < 16; ++k){
          hid[k] += v[c].x * w[k] + v[c].y * w[16 + k]
                  + v[c].z * w[32 + k] + v[c].w * w[48 + k];
        }
      }
      float s = 0.f;
      #pragma unroll
      for (int k = 0; k < 16; ++k) s += fast_tanh(hid[k]) * sW2[h * 16 + k];
      sc[h][b] = s;
    }
  }
  float a[BB][BB];
  #pragma unroll
  for (int h = 0; h < BB; ++h){
    float m = fmaxf(fmaxf(sc[h][0], sc[h][1]), sc[h][2]);
    float e0 = __expf(sc[h][0] - m), e1 = __expf(sc[h][1] - m), e2 = __expf(sc[h][2] - m);
    float inv = 1.f / (e0 + e1 + e2);
    a[h][0] = e0 * inv; a[h][1] = e1 * inv; a[h][2] = e2 * inv;
  }
  const float4* s0 = (const float4*)(acc + ((long long)0 * NN + n) * 64);
  const float4* s1 = (const float4*)(acc + ((long long)1 * NN + n) * 64);
  const float4* s2 = (const float4*)(acc + ((long long)2 * NN + n) * 64);
  #pragma unroll 4
  for (int c = 0; c < 16; ++c){
    float4 x0 = s0[c], x1 = s1[c], x2 = s2[c];
    x0.x *= 0.25f; x0.y *= 0.25f; x0.z *= 0.25f; x0.w *= 0.25f;
    x1.x *= 0.25f; x1.y *= 0.25f; x1.z *= 0.25f; x1.w *= 0.25f;
    x2.x *= 0.25f; x2.y *= 0.25f; x2.z *= 0.25f; x2.w *= 0.25f;
    for (int h = 0; h < BB; ++h){
      float4 o;
      o.x = a[h][0]*x0.x + a[h][1]*x1.x + a[h][2]*x2.x;
      o.y = a[h][0]*x0.y + a[h][1]*x1.y + a[h][2]*x2.y;
      o.z = a[h][0]*x0.z + a[h][1]*x1.z + a[h][2]*x2.z;
      o.w = a[h][0]*x0.w + a[h][1]*x1.w + a[h][2]*x2.w;
      long long dst;
      if (n < UCNT) dst = ((long long)h * UCNT + n) * 64;
      else          dst = (long long)BB * UCNT * 64 + ((long long)h * ICNT + (n - UCNT)) * 64;
      ((float4*)(out + dst))[c] = o;
    }
  }
}

// ---------------- launch ---------------------------------------------------
extern "C" void kernel_launch(void* const* d_in, const int* in_sizes, int n_in,
                              void* d_out, int out_size, void* d_ws, size_t ws_size,
                              hipStream_t stream){
  const float* ue   = (const float*)d_in[0];
  const float* ie   = (const float*)d_in[1];
  const float* W1   = (const float*)d_in[2];
  const float* W2   = (const float*)d_in[3];
  const float* vals = (const float*)d_in[4];
  const int*   rows = (const int*)d_in[5];
  const int*   cols = (const int*)d_in[6];
  float* out = (float*)d_out;

  char* ws = (char*)d_ws;
  size_t off = 0;
  auto alloc = [&](size_t bytes){ void* p = ws + off; off += (bytes + 255) & ~(size_t)255; return p; };
  float* cur  = (float*)alloc((size_t)BB * NN * 64 * 4);
  float* nxt  = (float*)alloc((size_t)BB * NN * 64 * 4);
  float* acc  = (float*)alloc((size_t)BB * NN * 64 * 4);
  float* cval = (float*)alloc((size_t)BB * NNZE * 4);
  int*   ccol = (int*)alloc((size_t)BB * NNZE * 4);
  int*   rp   = (int*)alloc((size_t)BB * (NN + 1) * 4);
  int*   tp   = (int*)alloc((size_t)BB * NN * 4);
  int*   cnt  = (int*)alloc((size_t)BB * NN * 4);
  (void)ws_size; (void)in_sizes; (void)n_in; (void)out_size;

  k_init<<<(BB * NN * 16 + 255) / 256, 256, 0, stream>>>(ue, ie, cur, acc);
  k_zero<<<(BB * NN + 255) / 256, 256, 0, stream>>>(cnt, (long long)BB * NN);
  k_hist<<<(BB * NNZE + 255) / 256, 256, 0, stream>>>(rows, cnt);
  k_scan<<<BB, 1024, 0, stream>>>(cnt, rp, tp);
  k_scatter<<<(BB * NNZE + 255) / 256, 256, 0, stream>>>(rows, cols, vals, tp, ccol, cval);

  float* a = cur; float* bfr = nxt;
  for (int l = 0; l < 3; ++l){
    k_spmm<<<(BB * NN + 3) / 4, 256, 0, stream>>>(rp, ccol, cval, a, bfr, acc);
    float* t = a; a = bfr; bfr = t;
  }
  k_att<<<(NN + 255) / 256, 256, 0, stream>>>(acc, W1, W2, out);
}

// Round 2
// 2111.113 us; speedup vs baseline: 1.1278x; 1.1278x over previous
//
#include <hip/hip_runtime.h>

#define UCNT 100000
#define ICNT 50000
#define BB   3
#define NNZE 2400000
#define NN   150000   // UCNT + ICNT

#define SCAN_CHUNK 4096           // elements per scan block (1024 thr x 4)
#define CPB ((NN + SCAN_CHUNK - 1) / SCAN_CHUNK)   // 37 chunks per behavior

// ---------------- init: cur = acc = ego (broadcast to 3 behaviors) ----------
__global__ __launch_bounds__(256) void k_init(const float* __restrict__ ue,
                                              const float* __restrict__ ie,
                                              float* __restrict__ cur,
                                              float* __restrict__ acc){
  long long idx = (long long)blockIdx.x * blockDim.x + threadIdx.x;  // float4 index
  const long long total = (long long)BB * NN * 16;
  if (idx >= total) return;
  long long within = idx % ((long long)NN * 16);
  long long n = within >> 4;
  int c = (int)(within & 15);
  float4 v;
  if (n < UCNT) v = ((const float4*)ue)[n * 16 + c];
  else          v = ((const float4*)ie)[(n - UCNT) * 16 + c];
  ((float4*)cur)[idx] = v;
  ((float4*)acc)[idx] = v;
}

__global__ __launch_bounds__(256) void k_zero(int* __restrict__ p, long long n){
  long long i = (long long)blockIdx.x * blockDim.x + threadIdx.x;
  if (i < n) p[i] = 0;
}

// ---------------- CSR build ------------------------------------------------
// hist: 4 edges per thread via int4 loads
__global__ __launch_bounds__(256) void k_hist(const int* __restrict__ rows,
                                              int* __restrict__ cnt){
  long long t = (long long)blockIdx.x * blockDim.x + threadIdx.x;
  long long i0 = t * 4;
  if (i0 >= (long long)BB * NNZE) return;
  int b = (int)(i0 / NNZE);          // NNZE % 4 == 0 -> all 4 same behavior
  int4 r = *(const int4*)(rows + i0);
  int* c = cnt + (long long)b * NN;
  atomicAdd(&c[r.x], 1);
  atomicAdd(&c[r.y], 1);
  atomicAdd(&c[r.z], 1);
  atomicAdd(&c[r.w], 1);
}

// scan level 1: per-chunk sums
__global__ __launch_bounds__(1024) void k_bsum(const int* __restrict__ cnt,
                                               int* __restrict__ bsum){
  int blk = blockIdx.x;              // b * CPB + c
  int b = blk / CPB, ch = blk - b * CPB;
  const int* src = cnt + (long long)b * NN;
  int base = ch * SCAN_CHUNK + threadIdx.x * 4;
  int s = 0;
  #pragma unroll
  for (int k = 0; k < 4; ++k){
    int i = base + k;
    if (i < NN) s += src[i];
  }
  __shared__ int sd[1024];
  sd[threadIdx.x] = s;
  __syncthreads();
  for (int off = 512; off > 0; off >>= 1){
    if (threadIdx.x < off) sd[threadIdx.x] += sd[threadIdx.x + off];
    __syncthreads();
  }
  if (threadIdx.x == 0) bsum[blk] = sd[0];
}

// scan level 2: tiny serial scan of chunk sums (per behavior), set rp[NN]
__global__ __launch_bounds__(64) void k_bscan(const int* __restrict__ bsum,
                                              int* __restrict__ boff,
                                              int* __restrict__ rp){
  int b = threadIdx.x;
  if (b >= BB) return;
  int run = 0;
  for (int c = 0; c < CPB; ++c){
    boff[b * CPB + c] = run;
    run += bsum[b * CPB + c];
  }
  rp[(long long)b * (NN + 1) + NN] = run;   // == NNZE
}

// scan level 3: per-chunk exclusive scan + chunk offset -> rp, tp
__global__ __launch_bounds__(1024) void k_scan2(const int* __restrict__ cnt,
                                                const int* __restrict__ boff,
                                                int* __restrict__ rp,
                                                int* __restrict__ tp){
  int blk = blockIdx.x;
  int b = blk / CPB, ch = blk - b * CPB;
  const int* src = cnt + (long long)b * NN;
  int* rpo = rp + (long long)b * (NN + 1);
  int* tpo = tp + (long long)b * NN;
  int base = ch * SCAN_CHUNK + threadIdx.x * 4;
  int v[4]; int tsum = 0;
  #pragma unroll
  for (int k = 0; k < 4; ++k){
    int i = base + k;
    v[k] = (i < NN) ? src[i] : 0;
    tsum += v[k];
  }
  __shared__ int sd[1024];
  sd[threadIdx.x] = tsum;
  __syncthreads();
  for (int off = 1; off < 1024; off <<= 1){
    int t = (threadIdx.x >= off) ? sd[threadIdx.x - off] : 0;
    __syncthreads();
    sd[threadIdx.x] += t;
    __syncthreads();
  }
  int excl = boff[blk] + sd[threadIdx.x] - tsum;
  #pragma unroll
  for (int k = 0; k < 4; ++k){
    int i = base + k;
    if (i < NN){ rpo[i] = excl; tpo[i] = excl; }
    excl += v[k];
  }
}

// scatter: packed {col, val} single 8B store per edge; 2 edges per thread
__global__ __launch_bounds__(256) void k_scatter(const int* __restrict__ rows,
                                                 const int* __restrict__ cols,
                                                 const float* __restrict__ vals,
                                                 int* __restrict__ tp,
                                                 int2* __restrict__ cpk){
  long long t = (long long)blockIdx.x * blockDim.x + threadIdx.x;
  long long i0 = t * 2;
  if (i0 >= (long long)BB * NNZE) return;
  int b = (int)(i0 / NNZE);          // NNZE even -> both edges same behavior
  int2 r = *(const int2*)(rows + i0);
  int2 c = *(const int2*)(cols + i0);
  float2 v = *(const float2*)(vals + i0);
  int* tpb = tp + (long long)b * NN;
  int2* dst = cpk + (long long)b * NNZE;
  int p0 = atomicAdd(&tpb[r.x], 1);
  dst[p0] = make_int2(c.x, __float_as_int(v.x));
  int p1 = atomicAdd(&tpb[r.y], 1);
  dst[p1] = make_int2(c.y, __float_as_int(v.y));
}

// ---------------- SpMM: one wave per (behavior,row), lane = element --------
template<bool LAST>
__global__ __launch_bounds__(256) void k_spmm(const int* __restrict__ rp,
                                              const int2* __restrict__ cpk,
                                              const float* __restrict__ cur,
                                              float* __restrict__ nxt,
                                              float* __restrict__ acc){
  int wid = blockIdx.x * (blockDim.x >> 6) + (threadIdx.x >> 6);
  int lane = threadIdx.x & 63;
  if (wid >= BB * NN) return;
  int b = wid / NN;
  int row = wid - b * NN;
  b   = __builtin_amdgcn_readfirstlane(b);
  row = __builtin_amdgcn_readfirstlane(row);
  const int* rpo = rp + (long long)b * (NN + 1);
  int s0 = __builtin_amdgcn_readfirstlane(rpo[row]);
  int s1 = __builtin_amdgcn_readfirstlane(rpo[row + 1]);
  const float* xb = cur + (long long)b * NN * 64;
  const int2*  pk = cpk + (long long)b * NNZE;
  float s = 0.f;
  int e = s0;
  for (; e + 1 < s1; e += 2){
    int2 q0 = pk[e];
    int2 q1 = pk[e + 1];
    int c0 = __builtin_amdgcn_readfirstlane(q0.x);
    int c1 = __builtin_amdgcn_readfirstlane(q1.x);
    s = fmaf(__int_as_float(q0.y), xb[(long long)c0 * 64 + lane], s);
    s = fmaf(__int_as_float(q1.y), xb[(long long)c1 * 64 + lane], s);
  }
  if (e < s1){
    int2 q0 = pk[e];
    int c0 = __builtin_amdgcn_readfirstlane(q0.x);
    s = fmaf(__int_as_float(q0.y), xb[(long long)c0 * 64 + lane], s);
  }
  long long o = (long long)wid * 64 + lane;
  if (!LAST) nxt[o] = s;
  acc[o] += s;
}

// ---------------- attention epilogue: one thread per node ------------------
__device__ __forceinline__ float fast_tanh(float x){
  float xc = fminf(fmaxf(x, -15.f), 15.f);
  float t = __expf(2.f * xc);
  return (t - 1.f) / (t + 1.f);
}

__global__ __launch_bounds__(256) void k_att(const float* __restrict__ acc,
                                             const float* __restrict__ W1,
                                             const float* __restrict__ W2,
                                             float* __restrict__ out){
  __shared__ float sW1[BB * 64 * 16];
  __shared__ float sW2[BB * 16];
  for (int i = threadIdx.x; i < BB * 64 * 16; i += blockDim.x) sW1[i] = W1[i];
  if (threadIdx.x < BB * 16) sW2[threadIdx.x] = W2[threadIdx.x];
  __syncthreads();
  int n = blockIdx.x * blockDim.x + threadIdx.x;
  if (n >= NN) return;

  float sc[BB][BB];   // [head][behavior]
  for (int b = 0; b < BB; ++b){
    const float4* src = (const float4*)(acc + ((long long)b * NN + n) * 64);
    float4 v[16];
    #pragma unroll
    for (int c = 0; c < 16; ++c){
      v[c] = src[c];
      v[c].x *= 0.25f; v[c].y *= 0.25f; v[c].z *= 0.25f; v[c].w *= 0.25f;
    }
    for (int h = 0; h < BB; ++h){
      float hid[16];
      #pragma unroll
      for (int k = 0; k < 16; ++k) hid[k] = 0.f;
      #pragma unroll
      for (int c = 0; c < 16; ++c){
        const float* w = &sW1[h * 1024 + c * 64];
        #pragma unroll
        for (int k = 0; k < 16; ++k){
          hid[k] += v[c].x * w[k] + v[c].y * w[16 + k]
                  + v[c].z * w[32 + k] + v[c].w * w[48 + k];
        }
      }
      float s = 0.f;
      #pragma unroll
      for (int k = 0; k < 16; ++k) s += fast_tanh(hid[k]) * sW2[h * 16 + k];
      sc[h][b] = s;
    }
  }
  float a[BB][BB];
  #pragma unroll
  for (int h = 0; h < BB; ++h){
    float m = fmaxf(fmaxf(sc[h][0], sc[h][1]), sc[h][2]);
    float e0 = __expf(sc[h][0] - m), e1 = __expf(sc[h][1] - m), e2 = __expf(sc[h][2] - m);
    float inv = 1.f / (e0 + e1 + e2);
    a[h][0] = e0 * inv; a[h][1] = e1 * inv; a[h][2] = e2 * inv;
  }
  const float4* s0 = (const float4*)(acc + ((long long)0 * NN + n) * 64);
  const float4* s1 = (const float4*)(acc + ((long long)1 * NN + n) * 64);
  const float4* s2 = (const float4*)(acc + ((long long)2 * NN + n) * 64);
  #pragma unroll 4
  for (int c = 0; c < 16; ++c){
    float4 x0 = s0[c], x1 = s1[c], x2 = s2[c];
    x0.x *= 0.25f; x0.y *= 0.25f; x0.z *= 0.25f; x0.w *= 0.25f;
    x1.x *= 0.25f; x1.y *= 0.25f; x1.z *= 0.25f; x1.w *= 0.25f;
    x2.x *= 0.25f; x2.y *= 0.25f; x2.z *= 0.25f; x2.w *= 0.25f;
    for (int h = 0; h < BB; ++h){
      float4 o;
      o.x = a[h][0]*x0.x + a[h][1]*x1.x + a[h][2]*x2.x;
      o.y = a[h][0]*x0.y + a[h][1]*x1.y + a[h][2]*x2.y;
      o.z = a[h][0]*x0.z + a[h][1]*x1.z + a[h][2]*x2.z;
      o.w = a[h][0]*x0.w + a[h][1]*x1.w + a[h][2]*x2.w;
      long long dst;
      if (n < UCNT) dst = ((long long)h * UCNT + n) * 64;
      else          dst = (long long)BB * UCNT * 64 + ((long long)h * ICNT + (n - UCNT)) * 64;
      ((float4*)(out + dst))[c] = o;
    }
  }
}

// ---------------- launch ---------------------------------------------------
extern "C" void kernel_launch(void* const* d_in, const int* in_sizes, int n_in,
                              void* d_out, int out_size, void* d_ws, size_t ws_size,
                              hipStream_t stream){
  const float* ue   = (const float*)d_in[0];
  const float* ie   = (const float*)d_in[1];
  const float* W1   = (const float*)d_in[2];
  const float* W2   = (const float*)d_in[3];
  const float* vals = (const float*)d_in[4];
  const int*   rows = (const int*)d_in[5];
  const int*   cols = (const int*)d_in[6];
  float* out = (float*)d_out;

  char* ws = (char*)d_ws;
  size_t off = 0;
  auto alloc = [&](size_t bytes){ void* p = ws + off; off += (bytes + 255) & ~(size_t)255; return p; };
  float* cur  = (float*)alloc((size_t)BB * NN * 64 * 4);
  float* nxt  = (float*)alloc((size_t)BB * NN * 64 * 4);
  float* acc  = (float*)alloc((size_t)BB * NN * 64 * 4);
  int2*  cpk  = (int2*)alloc((size_t)BB * NNZE * 8);
  int*   rp   = (int*)alloc((size_t)BB * (NN + 1) * 4);
  int*   tp   = (int*)alloc((size_t)BB * NN * 4);
  int*   cnt  = (int*)alloc((size_t)BB * NN * 4);
  int*   bsum = (int*)alloc((size_t)BB * CPB * 4);
  int*   boff = (int*)alloc((size_t)BB * CPB * 4);
  (void)ws_size; (void)in_sizes; (void)n_in; (void)out_size;

  k_init<<<(BB * NN * 16 + 255) / 256, 256, 0, stream>>>(ue, ie, cur, acc);
  k_zero<<<(BB * NN + 255) / 256, 256, 0, stream>>>(cnt, (long long)BB * NN);
  k_hist<<<(BB * NNZE / 4 + 255) / 256, 256, 0, stream>>>(rows, cnt);
  k_bsum<<<BB * CPB, 1024, 0, stream>>>(cnt, bsum);
  k_bscan<<<1, 64, 0, stream>>>(bsum, boff, rp);
  k_scan2<<<BB * CPB, 1024, 0, stream>>>(cnt, boff, rp, tp);
  k_scatter<<<(BB * NNZE / 2 + 255) / 256, 256, 0, stream>>>(rows, cols, vals, tp, cpk);

  float* a = cur; float* bfr = nxt;
  k_spmm<false><<<(BB * NN + 3) / 4, 256, 0, stream>>>(rp, cpk, a, bfr, acc);
  k_spmm<false><<<(BB * NN + 3) / 4, 256, 0, stream>>>(rp, cpk, bfr, a, acc);
  k_spmm<true ><<<(BB * NN + 3) / 4, 256, 0, stream>>>(rp, cpk, a, nullptr, acc);
  k_att<<<(NN + 255) / 256, 256, 0, stream>>>(acc, W1, W2, out);
}